// Round 1
// baseline (92.743 us; speedup 1.0000x reference)
//
#include <hip/hip_runtime.h>

// PPO loss fused pipeline for MI355X (gfx950).
// Kernels: prep (weights->bf16 transposed), gae1..4 (parallel affine scan),
// mlp (fused 2-layer tanh MLP + heads + per-row PPO loss partials), final reduce.

#define TT 65536

typedef float f32x4 __attribute__((ext_vector_type(4)));
typedef __bf16 bf16x8 __attribute__((ext_vector_type(8)));
typedef unsigned short u16x8 __attribute__((ext_vector_type(8)));

__device__ __forceinline__ unsigned short f2bf(float f) {
    // round-to-nearest-even fp32 -> bf16 (inputs are finite)
    unsigned int u = __float_as_uint(f);
    unsigned int r = (u + 0x7fffu + ((u >> 16) & 1u)) >> 16;
    return (unsigned short)r;
}

__device__ __forceinline__ void async_lds16(void* lds, const void* g) {
    __builtin_amdgcn_global_load_lds(
        (const __attribute__((address_space(1))) unsigned int*)g,
        (__attribute__((address_space(3))) unsigned int*)lds, 16, 0, 0);
}

// ---------------- prep: W1->W1T bf16 [256][512], W2->W2T [256][256], Wa/Wc -> WavT [32][256]
__global__ void k_prep(const float* __restrict__ W1, const float* __restrict__ W2,
                       const float* __restrict__ Wa, const float* __restrict__ Wc,
                       unsigned short* __restrict__ W1T, unsigned short* __restrict__ W2T,
                       unsigned short* __restrict__ WavT) {
    int idx = blockIdx.x * 256 + threadIdx.x;
    if (idx < 131072) {
        int n = idx >> 9, k = idx & 511;          // W1T[n][k] = W1[k][n]
        W1T[idx] = f2bf(W1[k * 256 + n]);
    } else if (idx < 196608) {
        int i = idx - 131072;
        int n = i >> 8, k = i & 255;              // W2T[n][k] = W2[k][n]
        W2T[i] = f2bf(W2[k * 256 + n]);
    } else if (idx < 204800) {
        int i = idx - 196608;
        int r = i >> 8, k = i & 255;              // rows 0-15: Wa^T, row 16: Wc^T, 17-31: 0
        float v = (r < 16) ? Wa[k * 16 + r] : ((r == 16) ? Wc[k] : 0.0f);
        WavT[i] = f2bf(v);
    }
}

// ---------------- GAE affine suffix scan helpers ----------------
// segment function a_t0 = D + C * a_t1 ; compose(L,R): C = C_L*C_R, D = D_L + C_L*D_R
__device__ __forceinline__ void suffix_scan256(float* sC, float* sD, int i) {
    float c = sC[i], d = sD[i];
#pragma unroll
    for (int s = 1; s < 256; s <<= 1) {
        float c2 = 1.0f, d2 = 0.0f;
        if (i + s < 256) { c2 = sC[i + s]; d2 = sD[i + s]; }
        __syncthreads();
        d = d + c * d2;
        c = c * c2;
        sC[i] = c; sD[i] = d;
        __syncthreads();
    }
}

__device__ __forceinline__ void gae_cd(const float* rewards, const float* terms,
                                       const float* values, int t, float* c, float* d) {
    float nt = 1.0f - terms[t];
    float nv = (t + 1 < TT) ? values[t + 1] : 0.0f;
    *d = rewards[t] + 0.99f * nv * nt - values[t];
    *c = 0.99f * 0.95f * nt;
}

__global__ void k_gae1(const float* __restrict__ rewards, const float* __restrict__ terms,
                       const float* __restrict__ values, float* __restrict__ aggC,
                       float* __restrict__ aggD) {
    __shared__ float sC[256], sD[256];
    int i = threadIdx.x;
    int t = blockIdx.x * 256 + i;
    float c, d;
    gae_cd(rewards, terms, values, t, &c, &d);
    sC[i] = c; sD[i] = d;
    __syncthreads();
    suffix_scan256(sC, sD, i);
    if (i == 0) { aggC[blockIdx.x] = sC[0]; aggD[blockIdx.x] = sD[0]; }
}

__global__ void k_gae2(const float* __restrict__ aggC, const float* __restrict__ aggD,
                       float* __restrict__ carry) {
    __shared__ float sC[256], sD[256];
    int i = threadIdx.x;
    sC[i] = aggC[i]; sD[i] = aggD[i];
    __syncthreads();
    suffix_scan256(sC, sD, i);
    // incoming value at right boundary of block i = suffix(i+1) applied to 0
    carry[i] = (i < 255) ? sD[i + 1] : 0.0f;
}

__global__ void k_gae3(const float* __restrict__ rewards, const float* __restrict__ terms,
                       const float* __restrict__ values, const float* __restrict__ carry,
                       float* __restrict__ adv, float* __restrict__ ret,
                       float* __restrict__ sumP) {
    __shared__ float sC[256], sD[256];
    int i = threadIdx.x, b = blockIdx.x;
    int t = b * 256 + i;
    float c, d;
    gae_cd(rewards, terms, values, t, &c, &d);
    sC[i] = c; sD[i] = d;
    __syncthreads();
    suffix_scan256(sC, sD, i);
    float a = sD[i] + sC[i] * carry[b];
    adv[t] = a;
    ret[t] = a + values[t];
    __syncthreads();
    sC[i] = a; sD[i] = a * a;
    __syncthreads();
#pragma unroll
    for (int s = 128; s > 0; s >>= 1) {
        if (i < s) { sC[i] += sC[i + s]; sD[i] += sD[i + s]; }
        __syncthreads();
    }
    if (i == 0) { sumP[2 * b] = sC[0]; sumP[2 * b + 1] = sD[0]; }
}

__global__ void k_gae4(const float* __restrict__ sumP, float* __restrict__ stats) {
    __shared__ float s1[256], s2[256];
    int i = threadIdx.x;
    s1[i] = sumP[2 * i]; s2[i] = sumP[2 * i + 1];
    __syncthreads();
#pragma unroll
    for (int s = 128; s > 0; s >>= 1) {
        if (i < s) { s1[i] += s1[i + s]; s2[i] += s2[i + s]; }
        __syncthreads();
    }
    if (i == 0) {
        float mean = s1[0] * (1.0f / TT);
        float var = s2[0] * (1.0f / TT) - mean * mean;
        float stdv = sqrtf(fmaxf(var, 0.0f));
        stats[0] = mean;
        stats[1] = 1.0f / (stdv + 1e-8f);
    }
}

// ---------------- fused MLP + heads + loss partials ----------------
// block = 64 rows, 256 threads (4 waves). Wave w computes cols [64w,64w+64) of the
// hidden layers; for the head, wave w owns rows [16w,16w+16).
// LDS swizzle (all tiles): element index col ^ ((row&7)<<3)  (16B-slot XOR within 128B).
__global__ __launch_bounds__(256, 2) void k_mlp(
    const float* __restrict__ obs, const int* __restrict__ actions,
    const float* __restrict__ logprobs, const float* __restrict__ values,
    const float* __restrict__ b1, const float* __restrict__ b2,
    const float* __restrict__ ba, const float* __restrict__ bc,
    const unsigned short* __restrict__ W1T, const unsigned short* __restrict__ W2T,
    const unsigned short* __restrict__ WavT, const float* __restrict__ adv,
    const float* __restrict__ ret, const float* __restrict__ stats,
    float* __restrict__ lossP) {
    __shared__ __align__(16) unsigned short smA[64 * 64];    // obs tile (bf16, swizzled)
    __shared__ __align__(16) unsigned short smB[256 * 64];   // weight tile (bf16, swizzled)
    __shared__ __align__(16) unsigned short smH[64 * 256];   // hidden1 then hidden
    __shared__ float smRed[4];

    const int tid = threadIdx.x;
    const int wid = tid >> 6;
    const int lane = tid & 63;
    const int cl = lane & 15;   // fragment column lane
    const int gg = lane >> 4;   // fragment k-group
    const int bm0 = blockIdx.x * 64;

    float b1v[4], b2v[4];
#pragma unroll
    for (int n = 0; n < 4; ++n) {
        int c = wid * 64 + n * 16 + cl;
        b1v[n] = b1[c];
        b2v[n] = b2[c];
    }
    const float bav = ba[cl];
    const float bc0 = bc[0];
    const float meanA = stats[0], rstdA = stats[1];

    f32x4 acc[4][4];
#pragma unroll
    for (int m = 0; m < 4; ++m)
#pragma unroll
        for (int n = 0; n < 4; ++n) acc[m][n] = (f32x4){0.f, 0.f, 0.f, 0.f};

    const int arow = tid >> 2;   // 0..63
    const int aseg = tid & 3;    // 0..3 (16 floats each)

    // ---------------- GEMM1: hidden1 = tanh(obs @ W1 + b1), K=512 ----------------
    for (int ks = 0; ks < 8; ++ks) {
        const int k0 = ks * 64;
        // stage A: 64x64 obs fp32 -> bf16, swizzled
        {
            const float* src = obs + (size_t)(bm0 + arow) * 512 + k0 + aseg * 16;
            float4 f0 = *(const float4*)(src);
            float4 f1 = *(const float4*)(src + 4);
            float4 f2 = *(const float4*)(src + 8);
            float4 f3 = *(const float4*)(src + 12);
            float fv[16];
            *(float4*)&fv[0] = f0; *(float4*)&fv[4] = f1;
            *(float4*)&fv[8] = f2; *(float4*)&fv[12] = f3;
            u16x8 c0, c1;
#pragma unroll
            for (int q = 0; q < 8; ++q) c0[q] = f2bf(fv[q]);
#pragma unroll
            for (int q = 0; q < 8; ++q) c1[q] = f2bf(fv[8 + q]);
            const int msk = (arow & 7) << 3;
            *(u16x8*)&smA[arow * 64 + ((aseg * 16) ^ msk)] = c0;
            *(u16x8*)&smA[arow * 64 + ((aseg * 16 + 8) ^ msk)] = c1;
        }
        // stage B: W1T rows 0..255, k-cols [k0,k0+64), pre-swizzled global source
#pragma unroll
        for (int it = 0; it < 8; ++it) {
            int chunk = it * 4 + wid;
            int n = chunk * 8 + (lane >> 3);
            int eoff = 8 * ((lane & 7) ^ (lane >> 3));
            async_lds16(&smB[chunk * 512], W1T + n * 512 + k0 + eoff);
        }
        __syncthreads();
#pragma unroll
        for (int s = 0; s < 2; ++s) {
            bf16x8 av[4], bv[4];
#pragma unroll
            for (int m = 0; m < 4; ++m) {
                int r = m * 16 + cl;
                av[m] = *(const bf16x8*)&smA[r * 64 + ((s * 32 + gg * 8) ^ ((r & 7) << 3))];
            }
#pragma unroll
            for (int n = 0; n < 4; ++n) {
                int rb = wid * 64 + n * 16 + cl;
                bv[n] = *(const bf16x8*)&smB[rb * 64 + ((s * 32 + gg * 8) ^ ((rb & 7) << 3))];
            }
#pragma unroll
            for (int m = 0; m < 4; ++m)
#pragma unroll
                for (int n = 0; n < 4; ++n)
                    acc[m][n] = __builtin_amdgcn_mfma_f32_16x16x32_bf16(av[m], bv[n], acc[m][n], 0, 0, 0);
        }
        __syncthreads();
    }
    // epilogue 1: tanh + bias -> smH (swizzled), reset acc
#pragma unroll
    for (int m = 0; m < 4; ++m)
#pragma unroll
        for (int n = 0; n < 4; ++n)
#pragma unroll
            for (int j = 0; j < 4; ++j) {
                int r = m * 16 + gg * 4 + j;
                int c = wid * 64 + n * 16 + cl;
                float v = tanhf(acc[m][n][j] + b1v[n]);
                smH[r * 256 + (c ^ ((r & 7) << 3))] = f2bf(v);
                acc[m][n][j] = 0.0f;
            }

    // ---------------- GEMM2: hidden = tanh(hidden1 @ W2 + b2), K=256 ----------------
    for (int ks = 0; ks < 4; ++ks) {
#pragma unroll
        for (int it = 0; it < 8; ++it) {
            int chunk = it * 4 + wid;
            int n = chunk * 8 + (lane >> 3);
            int eoff = 8 * ((lane & 7) ^ (lane >> 3));
            async_lds16(&smB[chunk * 512], W2T + n * 256 + ks * 64 + eoff);
        }
        __syncthreads();
#pragma unroll
        for (int s = 0; s < 2; ++s) {
            bf16x8 av[4], bv[4];
#pragma unroll
            for (int m = 0; m < 4; ++m) {
                int r = m * 16 + cl;
                av[m] = *(const bf16x8*)&smH[r * 256 + ((ks * 64 + s * 32 + gg * 8) ^ ((r & 7) << 3))];
            }
#pragma unroll
            for (int n = 0; n < 4; ++n) {
                int rb = wid * 64 + n * 16 + cl;
                bv[n] = *(const bf16x8*)&smB[rb * 64 + ((s * 32 + gg * 8) ^ ((rb & 7) << 3))];
            }
#pragma unroll
            for (int m = 0; m < 4; ++m)
#pragma unroll
                for (int n = 0; n < 4; ++n)
                    acc[m][n] = __builtin_amdgcn_mfma_f32_16x16x32_bf16(av[m], bv[n], acc[m][n], 0, 0, 0);
        }
        __syncthreads();
    }
    // epilogue 2: hidden -> smH (overwrite)
#pragma unroll
    for (int m = 0; m < 4; ++m)
#pragma unroll
        for (int n = 0; n < 4; ++n)
#pragma unroll
            for (int j = 0; j < 4; ++j) {
                int r = m * 16 + gg * 4 + j;
                int c = wid * 64 + n * 16 + cl;
                float v = tanhf(acc[m][n][j] + b2v[n]);
                smH[r * 256 + (c ^ ((r & 7) << 3))] = f2bf(v);
            }
    // stage WavT [32][256] -> smB
#pragma unroll
    for (int it = 0; it < 4; ++it) {
        int chunk = it * 4 + wid;
        int n = chunk * 2 + (lane >> 5);
        int e = (lane & 31) * 8;
        async_lds16(&smB[chunk * 512], WavT + n * 256 + (e ^ ((n & 7) << 3)));
    }
    __syncthreads();

    // ---------------- heads: logits (A=16) + value ----------------
    f32x4 acc_a = {0.f, 0.f, 0.f, 0.f}, acc_v = {0.f, 0.f, 0.f, 0.f};
#pragma unroll
    for (int kk = 0; kk < 8; ++kk) {
        int r = wid * 16 + cl;
        bf16x8 av = *(const bf16x8*)&smH[r * 256 + ((kk * 32 + gg * 8) ^ ((r & 7) << 3))];
        int ra = cl;
        bf16x8 bva = *(const bf16x8*)&smB[ra * 256 + ((kk * 32 + gg * 8) ^ ((ra & 7) << 3))];
        int rv = 16 + cl;
        bf16x8 bvv = *(const bf16x8*)&smB[rv * 256 + ((kk * 32 + gg * 8) ^ ((rv & 7) << 3))];
        acc_a = __builtin_amdgcn_mfma_f32_16x16x32_bf16(av, bva, acc_a, 0, 0, 0);
        acc_v = __builtin_amdgcn_mfma_f32_16x16x32_bf16(av, bvv, acc_v, 0, 0, 0);
    }

    // ---------------- per-row softmax + PPO loss ----------------
    float lsum = 0.0f;
    const int t0 = bm0 + wid * 16;
#pragma unroll
    for (int j = 0; j < 4; ++j) {
        int t = t0 + gg * 4 + j;
        float lg = acc_a[j] + bav;                       // logit[row t][action cl]
        float mx = lg;
#pragma unroll
        for (int dd = 1; dd < 16; dd <<= 1) mx = fmaxf(mx, __shfl_xor(mx, dd));
        float ex = expf(lg - mx);
        float se = ex;
#pragma unroll
        for (int dd = 1; dd < 16; dd <<= 1) se += __shfl_xor(se, dd);
        float ls = logf(se);
        float lp = lg - mx - ls;                          // log_softmax
        float pl = expf(lp) * lp;
        float ent = pl;
#pragma unroll
        for (int dd = 1; dd < 16; dd <<= 1) ent += __shfl_xor(ent, dd);
        ent = -ent;
        int act = actions[t];
        float newlp = __shfl(lp, (lane & 48) | act);
        float val = __shfl(acc_v[j], lane & 48) + bc0;

        float lpo = logprobs[t];
        float at = (adv[t] - meanA) * rstdA;
        float rt = ret[t];
        float vo = values[t];
        float ratio = expf(newlp - lpo);
        float rcl = fminf(fmaxf(ratio, 0.8f), 1.2f);
        float pg = fmaxf(-at * ratio, -at * rcl);
        float vcl = vo + fminf(fmaxf(val - vo, -0.2f), 0.2f);
        float dv = val - rt, dvc = vcl - rt;
        float vl = fmaxf(dv * dv, dvc * dvc);
        if (cl == 0) lsum += pg - 0.01f * ent + 0.25f * vl;
    }
    lsum += __shfl_xor(lsum, 16);
    lsum += __shfl_xor(lsum, 32);
    if (lane == 0) smRed[wid] = lsum;
    __syncthreads();
    if (tid == 0) lossP[blockIdx.x] = smRed[0] + smRed[1] + smRed[2] + smRed[3];
}

__global__ void k_final(const float* __restrict__ lossP, float* __restrict__ out) {
    __shared__ float s[256];
    int i = threadIdx.x;
    s[i] = lossP[i] + lossP[i + 256] + lossP[i + 512] + lossP[i + 768];
    __syncthreads();
#pragma unroll
    for (int st = 128; st > 0; st >>= 1) {
        if (i < st) s[i] += s[i + st];
        __syncthreads();
    }
    if (i == 0) out[0] = s[0] * (1.0f / TT);
}

extern "C" void kernel_launch(void* const* d_in, const int* in_sizes, int n_in,
                              void* d_out, int out_size, void* d_ws, size_t ws_size,
                              hipStream_t stream) {
    const float* obs      = (const float*)d_in[0];
    const int*   actions  = (const int*)d_in[1];
    const float* logprobs = (const float*)d_in[2];
    const float* rewards  = (const float*)d_in[3];
    const float* terms    = (const float*)d_in[4];
    const float* values   = (const float*)d_in[5];
    const float* W1 = (const float*)d_in[6];
    const float* b1 = (const float*)d_in[7];
    const float* W2 = (const float*)d_in[8];
    const float* b2 = (const float*)d_in[9];
    const float* Wa = (const float*)d_in[10];
    const float* ba = (const float*)d_in[11];
    const float* Wc = (const float*)d_in[12];
    const float* bc = (const float*)d_in[13];

    char* ws = (char*)d_ws;
    unsigned short* W1T  = (unsigned short*)(ws + 0);        // 262144 B
    unsigned short* W2T  = (unsigned short*)(ws + 262144);   // 131072 B
    unsigned short* WavT = (unsigned short*)(ws + 393216);   // 16384 B
    float* advp  = (float*)(ws + 409600);                    // 262144 B
    float* retp  = (float*)(ws + 671744);                    // 262144 B
    float* aggC  = (float*)(ws + 933888);                    // 1024 B
    float* aggD  = (float*)(ws + 934912);                    // 1024 B
    float* carry = (float*)(ws + 935936);                    // 1024 B
    float* sumP  = (float*)(ws + 936960);                    // 2048 B
    float* stats = (float*)(ws + 939008);                    // 64 B
    float* lossP = (float*)(ws + 939072);                    // 4096 B -> total ~943 KB

    k_prep<<<800, 256, 0, stream>>>(W1, W2, Wa, Wc, W1T, W2T, WavT);
    k_gae1<<<256, 256, 0, stream>>>(rewards, terms, values, aggC, aggD);
    k_gae2<<<1, 256, 0, stream>>>(aggC, aggD, carry);
    k_gae3<<<256, 256, 0, stream>>>(rewards, terms, values, carry, advp, retp, sumP);
    k_gae4<<<1, 256, 0, stream>>>(sumP, stats);
    k_mlp<<<1024, 256, 0, stream>>>(obs, actions, logprobs, values, b1, b2, ba, bc,
                                    W1T, W2T, WavT, advp, retp, stats, lossP);
    k_final<<<1, 256, 0, stream>>>(lossP, (float*)d_out);
}

// Round 2
// 67.387 us; speedup vs baseline: 1.3763x; 1.3763x over previous
//
#include <hip/hip_runtime.h>

// PPO loss fused pipeline for MI355X (gfx950).
// R1: fast tanh/exp/log (VALU was 40% busy on library tanhf), B-DMA issued
// before A-convert, prep+gae1 fused, gae2 folded into gae3 (5 launches).

#define TT 65536

typedef float f32x4 __attribute__((ext_vector_type(4)));
typedef __bf16 bf16x8 __attribute__((ext_vector_type(8)));
typedef unsigned short u16x8 __attribute__((ext_vector_type(8)));

__device__ __forceinline__ unsigned short f2bf(float f) {
    // round-to-nearest-even fp32 -> bf16 (inputs are finite)
    unsigned int u = __float_as_uint(f);
    unsigned int r = (u + 0x7fffu + ((u >> 16) & 1u)) >> 16;
    return (unsigned short)r;
}

// branch-free tanh: 1 - 2/(e^{2x}+1). Saturates correctly at +-inf of exp.
// ~6 VALU ops (mul, exp(native), add, rcp, fma) vs ~50 for library tanhf.
__device__ __forceinline__ float fast_tanh(float x) {
    float e = __expf(2.0f * x);
    return fmaf(-2.0f, __builtin_amdgcn_rcpf(e + 1.0f), 1.0f);
}

__device__ __forceinline__ void async_lds16(void* lds, const void* g) {
    __builtin_amdgcn_global_load_lds(
        (const __attribute__((address_space(1))) unsigned int*)g,
        (__attribute__((address_space(3))) unsigned int*)lds, 16, 0, 0);
}

// ---------------- GAE affine suffix scan helpers ----------------
// segment function a_t0 = D + C * a_t1 ; compose(L,R): C = C_L*C_R, D = D_L + C_L*D_R
__device__ __forceinline__ void suffix_scan256(float* sC, float* sD, int i) {
    float c = sC[i], d = sD[i];
#pragma unroll
    for (int s = 1; s < 256; s <<= 1) {
        float c2 = 1.0f, d2 = 0.0f;
        if (i + s < 256) { c2 = sC[i + s]; d2 = sD[i + s]; }
        __syncthreads();
        d = d + c * d2;
        c = c * c2;
        sC[i] = c; sD[i] = d;
        __syncthreads();
    }
}

__device__ __forceinline__ void gae_cd(const float* rewards, const float* terms,
                                       const float* values, int t, float* c, float* d) {
    float nt = 1.0f - terms[t];
    float nv = (t + 1 < TT) ? values[t + 1] : 0.0f;
    *d = rewards[t] + 0.99f * nv * nt - values[t];
    *c = 0.99f * 0.95f * nt;
}

// ---------------- fused prep + gae1 ----------------
// blocks 0..799: weight transpose+bf16; blocks 800..1055: GAE per-block suffix scan.
__global__ void k_prep_gae1(const float* __restrict__ W1, const float* __restrict__ W2,
                            const float* __restrict__ Wa, const float* __restrict__ Wc,
                            unsigned short* __restrict__ W1T, unsigned short* __restrict__ W2T,
                            unsigned short* __restrict__ WavT,
                            const float* __restrict__ rewards, const float* __restrict__ terms,
                            const float* __restrict__ values, float* __restrict__ aggC,
                            float* __restrict__ aggD) {
    if (blockIdx.x < 800) {
        int idx = blockIdx.x * 256 + threadIdx.x;
        if (idx < 131072) {
            int n = idx >> 9, k = idx & 511;          // W1T[n][k] = W1[k][n]
            W1T[idx] = f2bf(W1[k * 256 + n]);
        } else if (idx < 196608) {
            int i = idx - 131072;
            int n = i >> 8, k = i & 255;              // W2T[n][k] = W2[k][n]
            W2T[i] = f2bf(W2[k * 256 + n]);
        } else if (idx < 204800) {
            int i = idx - 196608;
            int r = i >> 8, k = i & 255;              // rows 0-15: Wa^T, row 16: Wc^T, 17-31: 0
            float v = (r < 16) ? Wa[k * 16 + r] : ((r == 16) ? Wc[k] : 0.0f);
            WavT[i] = f2bf(v);
        }
        return;
    }
    __shared__ float sC[256], sD[256];
    int i = threadIdx.x;
    int b = blockIdx.x - 800;
    int t = b * 256 + i;
    float c, d;
    gae_cd(rewards, terms, values, t, &c, &d);
    sC[i] = c; sD[i] = d;
    __syncthreads();
    suffix_scan256(sC, sD, i);
    if (i == 0) { aggC[b] = sC[0]; aggD[b] = sD[0]; }
}

// ---------------- gae3 (absorbs old gae2's aggregate scan) ----------------
__global__ void k_gae3(const float* __restrict__ rewards, const float* __restrict__ terms,
                       const float* __restrict__ values, const float* __restrict__ aggC,
                       const float* __restrict__ aggD, float* __restrict__ adv,
                       float* __restrict__ ret, float* __restrict__ sumP) {
    __shared__ float sC[256], sD[256];
    int i = threadIdx.x, b = blockIdx.x;
    // aggregate suffix scan (redundant per block, cheap) -> carry into block b
    sC[i] = aggC[i]; sD[i] = aggD[i];
    __syncthreads();
    suffix_scan256(sC, sD, i);
    float carry = (b < 255) ? sD[b + 1] : 0.0f;   // broadcast read
    __syncthreads();

    int t = b * 256 + i;
    float c, d;
    gae_cd(rewards, terms, values, t, &c, &d);
    sC[i] = c; sD[i] = d;
    __syncthreads();
    suffix_scan256(sC, sD, i);
    float a = sD[i] + sC[i] * carry;
    adv[t] = a;
    ret[t] = a + values[t];
    __syncthreads();
    sC[i] = a; sD[i] = a * a;
    __syncthreads();
#pragma unroll
    for (int s = 128; s > 0; s >>= 1) {
        if (i < s) { sC[i] += sC[i + s]; sD[i] += sD[i + s]; }
        __syncthreads();
    }
    if (i == 0) { sumP[2 * b] = sC[0]; sumP[2 * b + 1] = sD[0]; }
}

__global__ void k_gae4(const float* __restrict__ sumP, float* __restrict__ stats) {
    __shared__ float s1[256], s2[256];
    int i = threadIdx.x;
    s1[i] = sumP[2 * i]; s2[i] = sumP[2 * i + 1];
    __syncthreads();
#pragma unroll
    for (int s = 128; s > 0; s >>= 1) {
        if (i < s) { s1[i] += s1[i + s]; s2[i] += s2[i + s]; }
        __syncthreads();
    }
    if (i == 0) {
        float mean = s1[0] * (1.0f / TT);
        float var = s2[0] * (1.0f / TT) - mean * mean;
        float stdv = sqrtf(fmaxf(var, 0.0f));
        stats[0] = mean;
        stats[1] = 1.0f / (stdv + 1e-8f);
    }
}

// ---------------- fused MLP + heads + loss partials ----------------
// block = 64 rows, 256 threads (4 waves). Wave w computes cols [64w,64w+64) of the
// hidden layers; for the head, wave w owns rows [16w,16w+16).
// LDS swizzle (all tiles): element index col ^ ((row&7)<<3)  (16B-slot XOR within 128B).
__global__ __launch_bounds__(256, 2) void k_mlp(
    const float* __restrict__ obs, const int* __restrict__ actions,
    const float* __restrict__ logprobs, const float* __restrict__ values,
    const float* __restrict__ b1, const float* __restrict__ b2,
    const float* __restrict__ ba, const float* __restrict__ bc,
    const unsigned short* __restrict__ W1T, const unsigned short* __restrict__ W2T,
    const unsigned short* __restrict__ WavT, const float* __restrict__ adv,
    const float* __restrict__ ret, const float* __restrict__ stats,
    float* __restrict__ lossP) {
    __shared__ __align__(16) unsigned short smA[64 * 64];    // obs tile (bf16, swizzled)
    __shared__ __align__(16) unsigned short smB[256 * 64];   // weight tile (bf16, swizzled)
    __shared__ __align__(16) unsigned short smH[64 * 256];   // hidden1 then hidden
    __shared__ float smRed[4];

    const int tid = threadIdx.x;
    const int wid = tid >> 6;
    const int lane = tid & 63;
    const int cl = lane & 15;   // fragment column lane
    const int gg = lane >> 4;   // fragment k-group
    const int bm0 = blockIdx.x * 64;

    float b1v[4], b2v[4];
#pragma unroll
    for (int n = 0; n < 4; ++n) {
        int c = wid * 64 + n * 16 + cl;
        b1v[n] = b1[c];
        b2v[n] = b2[c];
    }
    const float bav = ba[cl];
    const float bc0 = bc[0];
    const float meanA = stats[0], rstdA = stats[1];

    f32x4 acc[4][4];
#pragma unroll
    for (int m = 0; m < 4; ++m)
#pragma unroll
        for (int n = 0; n < 4; ++n) acc[m][n] = (f32x4){0.f, 0.f, 0.f, 0.f};

    const int arow = tid >> 2;   // 0..63
    const int aseg = tid & 3;    // 0..3 (16 floats each)

    // ---------------- GEMM1: hidden1 = tanh(obs @ W1 + b1), K=512 ----------------
    for (int ks = 0; ks < 8; ++ks) {
        const int k0 = ks * 64;
        // issue B DMA first so it overlaps the A convert VALU below
#pragma unroll
        for (int it = 0; it < 8; ++it) {
            int chunk = it * 4 + wid;
            int n = chunk * 8 + (lane >> 3);
            int eoff = 8 * ((lane & 7) ^ (lane >> 3));
            async_lds16(&smB[chunk * 512], W1T + n * 512 + k0 + eoff);
        }
        // stage A: 64x64 obs fp32 -> bf16, swizzled
        {
            const float* src = obs + (size_t)(bm0 + arow) * 512 + k0 + aseg * 16;
            float4 f0 = *(const float4*)(src);
            float4 f1 = *(const float4*)(src + 4);
            float4 f2 = *(const float4*)(src + 8);
            float4 f3 = *(const float4*)(src + 12);
            float fv[16];
            *(float4*)&fv[0] = f0; *(float4*)&fv[4] = f1;
            *(float4*)&fv[8] = f2; *(float4*)&fv[12] = f3;
            u16x8 c0, c1;
#pragma unroll
            for (int q = 0; q < 8; ++q) c0[q] = f2bf(fv[q]);
#pragma unroll
            for (int q = 0; q < 8; ++q) c1[q] = f2bf(fv[8 + q]);
            const int msk = (arow & 7) << 3;
            *(u16x8*)&smA[arow * 64 + ((aseg * 16) ^ msk)] = c0;
            *(u16x8*)&smA[arow * 64 + ((aseg * 16 + 8) ^ msk)] = c1;
        }
        __syncthreads();
#pragma unroll
        for (int s = 0; s < 2; ++s) {
            bf16x8 av[4], bv[4];
#pragma unroll
            for (int m = 0; m < 4; ++m) {
                int r = m * 16 + cl;
                av[m] = *(const bf16x8*)&smA[r * 64 + ((s * 32 + gg * 8) ^ ((r & 7) << 3))];
            }
#pragma unroll
            for (int n = 0; n < 4; ++n) {
                int rb = wid * 64 + n * 16 + cl;
                bv[n] = *(const bf16x8*)&smB[rb * 64 + ((s * 32 + gg * 8) ^ ((rb & 7) << 3))];
            }
#pragma unroll
            for (int m = 0; m < 4; ++m)
#pragma unroll
                for (int n = 0; n < 4; ++n)
                    acc[m][n] = __builtin_amdgcn_mfma_f32_16x16x32_bf16(av[m], bv[n], acc[m][n], 0, 0, 0);
        }
        __syncthreads();
    }
    // epilogue 1: tanh + bias -> smH (swizzled), reset acc
#pragma unroll
    for (int m = 0; m < 4; ++m)
#pragma unroll
        for (int n = 0; n < 4; ++n)
#pragma unroll
            for (int j = 0; j < 4; ++j) {
                int r = m * 16 + gg * 4 + j;
                int c = wid * 64 + n * 16 + cl;
                float v = fast_tanh(acc[m][n][j] + b1v[n]);
                smH[r * 256 + (c ^ ((r & 7) << 3))] = f2bf(v);
                acc[m][n][j] = 0.0f;
            }

    // ---------------- GEMM2: hidden = tanh(hidden1 @ W2 + b2), K=256 ----------------
    for (int ks = 0; ks < 4; ++ks) {
#pragma unroll
        for (int it = 0; it < 8; ++it) {
            int chunk = it * 4 + wid;
            int n = chunk * 8 + (lane >> 3);
            int eoff = 8 * ((lane & 7) ^ (lane >> 3));
            async_lds16(&smB[chunk * 512], W2T + n * 256 + ks * 64 + eoff);
        }
        __syncthreads();
#pragma unroll
        for (int s = 0; s < 2; ++s) {
            bf16x8 av[4], bv[4];
#pragma unroll
            for (int m = 0; m < 4; ++m) {
                int r = m * 16 + cl;
                av[m] = *(const bf16x8*)&smH[r * 256 + ((ks * 64 + s * 32 + gg * 8) ^ ((r & 7) << 3))];
            }
#pragma unroll
            for (int n = 0; n < 4; ++n) {
                int rb = wid * 64 + n * 16 + cl;
                bv[n] = *(const bf16x8*)&smB[rb * 64 + ((s * 32 + gg * 8) ^ ((rb & 7) << 3))];
            }
#pragma unroll
            for (int m = 0; m < 4; ++m)
#pragma unroll
                for (int n = 0; n < 4; ++n)
                    acc[m][n] = __builtin_amdgcn_mfma_f32_16x16x32_bf16(av[m], bv[n], acc[m][n], 0, 0, 0);
        }
        __syncthreads();
    }
    // epilogue 2: hidden -> smH (overwrite)
#pragma unroll
    for (int m = 0; m < 4; ++m)
#pragma unroll
        for (int n = 0; n < 4; ++n)
#pragma unroll
            for (int j = 0; j < 4; ++j) {
                int r = m * 16 + gg * 4 + j;
                int c = wid * 64 + n * 16 + cl;
                float v = fast_tanh(acc[m][n][j] + b2v[n]);
                smH[r * 256 + (c ^ ((r & 7) << 3))] = f2bf(v);
            }
    // stage WavT [32][256] -> smB
#pragma unroll
    for (int it = 0; it < 4; ++it) {
        int chunk = it * 4 + wid;
        int n = chunk * 2 + (lane >> 5);
        int e = (lane & 31) * 8;
        async_lds16(&smB[chunk * 512], WavT + n * 256 + (e ^ ((n & 7) << 3)));
    }
    __syncthreads();

    // ---------------- heads: logits (A=16) + value ----------------
    f32x4 acc_a = {0.f, 0.f, 0.f, 0.f}, acc_v = {0.f, 0.f, 0.f, 0.f};
#pragma unroll
    for (int kk = 0; kk < 8; ++kk) {
        int r = wid * 16 + cl;
        bf16x8 av = *(const bf16x8*)&smH[r * 256 + ((kk * 32 + gg * 8) ^ ((r & 7) << 3))];
        int ra = cl;
        bf16x8 bva = *(const bf16x8*)&smB[ra * 256 + ((kk * 32 + gg * 8) ^ ((ra & 7) << 3))];
        int rv = 16 + cl;
        bf16x8 bvv = *(const bf16x8*)&smB[rv * 256 + ((kk * 32 + gg * 8) ^ ((rv & 7) << 3))];
        acc_a = __builtin_amdgcn_mfma_f32_16x16x32_bf16(av, bva, acc_a, 0, 0, 0);
        acc_v = __builtin_amdgcn_mfma_f32_16x16x32_bf16(av, bvv, acc_v, 0, 0, 0);
    }

    // ---------------- per-row softmax + PPO loss ----------------
    float lsum = 0.0f;
    const int t0 = bm0 + wid * 16;
#pragma unroll
    for (int j = 0; j < 4; ++j) {
        int t = t0 + gg * 4 + j;
        float lg = acc_a[j] + bav;                       // logit[row t][action cl]
        float mx = lg;
#pragma unroll
        for (int dd = 1; dd < 16; dd <<= 1) mx = fmaxf(mx, __shfl_xor(mx, dd));
        float ex = __expf(lg - mx);
        float se = ex;
#pragma unroll
        for (int dd = 1; dd < 16; dd <<= 1) se += __shfl_xor(se, dd);
        float ls = __logf(se);
        float lp = lg - mx - ls;                          // log_softmax
        float pl = __expf(lp) * lp;
        float ent = pl;
#pragma unroll
        for (int dd = 1; dd < 16; dd <<= 1) ent += __shfl_xor(ent, dd);
        ent = -ent;
        int act = actions[t];
        float newlp = __shfl(lp, (lane & 48) | act);
        float val = __shfl(acc_v[j], lane & 48) + bc0;

        float lpo = logprobs[t];
        float at = (adv[t] - meanA) * rstdA;
        float rt = ret[t];
        float vo = values[t];
        float ratio = __expf(newlp - lpo);
        float rcl = fminf(fmaxf(ratio, 0.8f), 1.2f);
        float pg = fmaxf(-at * ratio, -at * rcl);
        float vcl = vo + fminf(fmaxf(val - vo, -0.2f), 0.2f);
        float dv = val - rt, dvc = vcl - rt;
        float vl = fmaxf(dv * dv, dvc * dvc);
        if (cl == 0) lsum += pg - 0.01f * ent + 0.25f * vl;
    }
    lsum += __shfl_xor(lsum, 16);
    lsum += __shfl_xor(lsum, 32);
    if (lane == 0) smRed[wid] = lsum;
    __syncthreads();
    if (tid == 0) lossP[blockIdx.x] = smRed[0] + smRed[1] + smRed[2] + smRed[3];
}

__global__ void k_final(const float* __restrict__ lossP, float* __restrict__ out) {
    __shared__ float s[256];
    int i = threadIdx.x;
    s[i] = lossP[i] + lossP[i + 256] + lossP[i + 512] + lossP[i + 768];
    __syncthreads();
#pragma unroll
    for (int st = 128; st > 0; st >>= 1) {
        if (i < st) s[i] += s[i + st];
        __syncthreads();
    }
    if (i == 0) out[0] = s[0] * (1.0f / TT);
}

extern "C" void kernel_launch(void* const* d_in, const int* in_sizes, int n_in,
                              void* d_out, int out_size, void* d_ws, size_t ws_size,
                              hipStream_t stream) {
    const float* obs      = (const float*)d_in[0];
    const int*   actions  = (const int*)d_in[1];
    const float* logprobs = (const float*)d_in[2];
    const float* rewards  = (const float*)d_in[3];
    const float* terms    = (const float*)d_in[4];
    const float* values   = (const float*)d_in[5];
    const float* W1 = (const float*)d_in[6];
    const float* b1 = (const float*)d_in[7];
    const float* W2 = (const float*)d_in[8];
    const float* b2 = (const float*)d_in[9];
    const float* Wa = (const float*)d_in[10];
    const float* ba = (const float*)d_in[11];
    const float* Wc = (const float*)d_in[12];
    const float* bc = (const float*)d_in[13];

    char* ws = (char*)d_ws;
    unsigned short* W1T  = (unsigned short*)(ws + 0);        // 262144 B
    unsigned short* W2T  = (unsigned short*)(ws + 262144);   // 131072 B
    unsigned short* WavT = (unsigned short*)(ws + 393216);   // 16384 B
    float* advp  = (float*)(ws + 409600);                    // 262144 B
    float* retp  = (float*)(ws + 671744);                    // 262144 B
    float* aggC  = (float*)(ws + 933888);                    // 1024 B
    float* aggD  = (float*)(ws + 934912);                    // 1024 B
    float* sumP  = (float*)(ws + 936960);                    // 2048 B
    float* stats = (float*)(ws + 939008);                    // 64 B
    float* lossP = (float*)(ws + 939072);                    // 4096 B -> total ~943 KB

    k_prep_gae1<<<1056, 256, 0, stream>>>(W1, W2, Wa, Wc, W1T, W2T, WavT,
                                          rewards, terms, values, aggC, aggD);
    k_gae3<<<256, 256, 0, stream>>>(rewards, terms, values, aggC, aggD, advp, retp, sumP);
    k_gae4<<<1, 256, 0, stream>>>(sumP, stats);
    k_mlp<<<1024, 256, 0, stream>>>(obs, actions, logprobs, values, b1, b2, ba, bc,
                                    W1T, W2T, WavT, advp, retp, stats, lossP);
    k_final<<<1, 256, 0, stream>>>(lossP, (float*)d_out);
}